// Round 3
// baseline (161.386 us; speedup 1.0000x reference)
//
#include <hip/hip_runtime.h>
#include <math.h>

#define B_TOT 8192
#define N_PTS 512
#define WAVES_PER_BLOCK 4
#define BLK_A (64 * WAVES_PER_BLOCK)
// 2 batches per wave -> 4096 waves -> 1024 blocks
#define GRID_A (B_TOT / (2 * WAVES_PER_BLOCK))

// 12-byte point => global_load_dwordx3, 768 contiguous bytes per wave-instruction.
struct f3 { float x, y, z; };

// Full-wave (64-lane) sum via DPP — no DS pipe. Total lands in LANE 63.
__device__ __forceinline__ float dpp_wave_sum(float v) {
    int x;
    x = __builtin_amdgcn_update_dpp(0, __float_as_int(v), 0x111, 0xF, 0xF, true);
    v += __int_as_float(x);
    x = __builtin_amdgcn_update_dpp(0, __float_as_int(v), 0x112, 0xF, 0xF, true);
    v += __int_as_float(x);
    x = __builtin_amdgcn_update_dpp(0, __float_as_int(v), 0x114, 0xF, 0xF, true);
    v += __int_as_float(x);
    x = __builtin_amdgcn_update_dpp(0, __float_as_int(v), 0x118, 0xF, 0xF, true);
    v += __int_as_float(x);
    x = __builtin_amdgcn_update_dpp(0, __float_as_int(v), 0x142, 0xF, 0xF, true);
    v += __int_as_float(x);
    x = __builtin_amdgcn_update_dpp(0, __float_as_int(v), 0x143, 0xF, 0xF, true);
    v += __int_as_float(x);
    return v;  // lane 63 holds the wave total
}

__device__ __forceinline__ void accum17(float* a, const f3& X, const f3& Y) {
    a[0] += X.x;  a[1] += X.y;  a[2] += X.z;
    a[3] += Y.x;  a[4] += Y.y;  a[5] += Y.z;
    a[6]  += X.x*Y.x; a[7]  += X.x*Y.y; a[8]  += X.x*Y.z;
    a[9]  += X.y*Y.x; a[10] += X.y*Y.y; a[11] += X.y*Y.z;
    a[12] += X.z*Y.x; a[13] += X.z*Y.y; a[14] += X.z*Y.z;
    a[15] += X.x*X.x + X.y*X.y + X.z*X.z;
    a[16] += Y.x*Y.x + Y.y*Y.y + Y.z*Y.z;
}

// Closed-form per-batch Kabsch residual from the 17 sums (f64, unchanged math).
__device__ __forceinline__ double kabsch_v(const double* S) {
    const double Nn = (double)N_PTS;
    double mx[3] = {S[0]/Nn, S[1]/Nn, S[2]/Nn};
    double my[3] = {S[3]/Nn, S[4]/Nn, S[5]/Nn};

    double C[3][3];
    #pragma unroll
    for (int d = 0; d < 3; d++)
        #pragma unroll
        for (int e = 0; e < 3; e++)
            C[d][e] = S[6 + d*3 + e] - Nn * mx[d] * my[e];

    double sxx = S[15] - Nn*(mx[0]*mx[0] + mx[1]*mx[1] + mx[2]*mx[2]);
    double syy = S[16] - Nn*(my[0]*my[0] + my[1]*my[1] + my[2]*my[2]);

    double K00=0,K01=0,K02=0,K11=0,K12=0,K22=0;
    #pragma unroll
    for (int k = 0; k < 3; k++) {
        K00 += C[k][0]*C[k][0]; K01 += C[k][0]*C[k][1]; K02 += C[k][0]*C[k][2];
        K11 += C[k][1]*C[k][1]; K12 += C[k][1]*C[k][2]; K22 += C[k][2]*C[k][2];
    }

    double q3 = (K00 + K11 + K22) / 3.0;
    double p1 = K01*K01 + K02*K02 + K12*K12;
    double a00 = K00 - q3, a11 = K11 - q3, a22 = K22 - q3;
    double p2 = a00*a00 + a11*a11 + a22*a22 + 2.0*p1;
    double lam1, lam2, lam3;
    if (p2 <= 1e-300) {
        lam1 = lam2 = lam3 = q3;
    } else {
        double pp  = sqrt(p2 / 6.0);
        double ip  = 1.0 / pp;
        double b00 = a00*ip, b11 = a11*ip, b22 = a22*ip;
        double b01 = K01*ip, b02 = K02*ip, b12 = K12*ip;
        double detB = b00*(b11*b22 - b12*b12)
                    - b01*(b01*b22 - b12*b02)
                    + b02*(b01*b12 - b11*b02);
        double r = 0.5 * detB;
        r = fmin(1.0, fmax(-1.0, r));
        double phi = acos(r) / 3.0;
        lam1 = q3 + 2.0*pp*cos(phi);
        lam3 = q3 + 2.0*pp*cos(phi + 2.0943951023931954923);  // +2*pi/3
        lam2 = 3.0*q3 - lam1 - lam3;
    }
    lam1 = fmax(lam1, 0.0); lam2 = fmax(lam2, 0.0); lam3 = fmax(lam3, 0.0);
    double s1 = sqrt(lam1), s2 = sqrt(lam2), s3 = sqrt(lam3);

    double detC = C[0][0]*(C[1][1]*C[2][2] - C[1][2]*C[2][1])
                - C[0][1]*(C[1][0]*C[2][2] - C[1][2]*C[2][0])
                + C[0][2]*(C[1][0]*C[2][1] - C[1][1]*C[2][0]);
    double sgn = (detC < 0.0) ? -1.0 : 1.0;
    double trRC = s1 + s2 + sgn * s3;

    return sxx + syy - 2.0 * trRC;
}

// ---------------- Single fused kernel --------------------------------------
// One wave per TWO consecutive batches (their 24 KB are contiguous in memory).
// Lane loads points {64p + lane, p=0..15} of the 1024-point pair region:
// p<8 = batch A (identical per-batch accumulation order as before), p>=8 = B.
// After DPP reduce, batch-B totals are broadcast; lanes 62 & 63 run the two
// f64 solves SIMD-parallel (halves the serial solve tail per SIMD).
// Per-block f64 atomicAdd + arrival counter; last block writes the mean.
__global__ __launch_bounds__(BLK_A) void fused_kernel(const float* __restrict__ x,
                                                      const float* __restrict__ y,
                                                      double* __restrict__ acc_out,
                                                      unsigned* __restrict__ cnt,
                                                      float* __restrict__ out)
{
    const int wave = threadIdx.x >> 6;
    const int lane = threadIdx.x & 63;
    const int pair = blockIdx.x * WAVES_PER_BLOCK + wave;   // 0..4095

    const f3* __restrict__ xb = reinterpret_cast<const f3*>(x) + (size_t)pair * 2 * N_PTS;
    const f3* __restrict__ yb = reinterpret_cast<const f3*>(y) + (size_t)pair * 2 * N_PTS;

    float aA[17], aB[17];
    #pragma unroll
    for (int k = 0; k < 17; k++) { aA[k] = 0.f; aB[k] = 0.f; }

    #pragma unroll
    for (int p = 0; p < 8; p++) {
        f3 X = xb[p * 64 + lane];
        f3 Y = yb[p * 64 + lane];
        accum17(aA, X, Y);
    }
    #pragma unroll
    for (int p = 8; p < 16; p++) {
        f3 X = xb[p * 64 + lane];
        f3 Y = yb[p * 64 + lane];
        accum17(aB, X, Y);
    }

    #pragma unroll
    for (int k = 0; k < 17; k++) { aA[k] = dpp_wave_sum(aA[k]); aB[k] = dpp_wave_sum(aB[k]); }

    // broadcast batch-B totals (live in lane 63) to all lanes
    float sB[17];
    #pragma unroll
    for (int k = 0; k < 17; k++) sB[k] = __shfl(aB[k], 63, 64);

    double v = 0.0;
    if (lane >= 62) {
        double S[17];
        #pragma unroll
        for (int k = 0; k < 17; k++)
            S[k] = (lane == 63) ? (double)aA[k] : (double)sB[k];
        v = kabsch_v(S);   // lane 63: batch A, lane 62: batch B
    }

    // lane 62 ends with wave total (v62 + v63)
    double vsum = v + __shfl_down(v, 1, 64);

    __shared__ double red[WAVES_PER_BLOCK];
    if (lane == 62) red[wave] = vsum;
    __syncthreads();

    if (threadIdx.x == 0) {
        double blk = red[0] + red[1] + red[2] + red[3];
        atomicAdd(acc_out, blk);
        __threadfence();
        unsigned t = atomicAdd(cnt, 1u);
        if (t == gridDim.x - 1) {
            __threadfence();
            double total = atomicAdd(acc_out, 0.0);  // atomic read at L2
            out[0] = (float)(total / ((double)B_TOT * (double)N_PTS * 3.0));
        }
    }
}

extern "C" void kernel_launch(void* const* d_in, const int* in_sizes, int n_in,
                              void* d_out, int out_size, void* d_ws, size_t ws_size,
                              hipStream_t stream) {
    const float* x = (const float*)d_in[0];   // input  (B,N,3) fp32
    const float* y = (const float*)d_in[1];   // target (B,N,3) fp32
    float* out = (float*)d_out;

    double*   acc = (double*)d_ws;                      // 8 B
    unsigned* cnt = (unsigned*)((char*)d_ws + 8);       // 4 B

    hipMemsetAsync(d_ws, 0, 16, stream);                // zero acc + cnt (graph-capturable)
    fused_kernel<<<GRID_A, BLK_A, 0, stream>>>(x, y, acc, cnt, out);
}

// Round 4
// 115.853 us; speedup vs baseline: 1.3930x; 1.3930x over previous
//
#include <hip/hip_runtime.h>
#include <math.h>

#define B_TOT 8192
#define N_PTS 512
#define WAVES_PER_BLOCK 4
#define BLK_A (64 * WAVES_PER_BLOCK)

// 12-byte point; align 4 so loads compile to contiguous dwordx3 (or dword+dwordx2).
struct f3 { float x, y, z; };

// Full-wave (64-lane) sum via DPP — no DS pipe. Total lands in LANE 63.
__device__ __forceinline__ float dpp_wave_sum(float v) {
    int x;
    x = __builtin_amdgcn_update_dpp(0, __float_as_int(v), 0x111, 0xF, 0xF, true);
    v += __int_as_float(x);
    x = __builtin_amdgcn_update_dpp(0, __float_as_int(v), 0x112, 0xF, 0xF, true);
    v += __int_as_float(x);
    x = __builtin_amdgcn_update_dpp(0, __float_as_int(v), 0x114, 0xF, 0xF, true);
    v += __int_as_float(x);
    x = __builtin_amdgcn_update_dpp(0, __float_as_int(v), 0x118, 0xF, 0xF, true);
    v += __int_as_float(x);
    x = __builtin_amdgcn_update_dpp(0, __float_as_int(v), 0x142, 0xF, 0xF, true);
    v += __int_as_float(x);
    x = __builtin_amdgcn_update_dpp(0, __float_as_int(v), 0x143, 0xF, 0xF, true);
    v += __int_as_float(x);
    return v;  // lane 63 holds the wave total
}

// ---------------- Kernel A: per-batch raw sums (fp32, bandwidth-bound) -------
// One wave per batch. Lane handles points {64k + lane, k=0..7} => every wave
// load instruction covers 768 contiguous bytes, fully consumed immediately.
// acc: [0..2] Sx, [3..5] Sy, [6..14] Sxy (d*3+e), [15] Sxx, [16] Syy
// Output TRANSPOSED: ws[k*B_TOT + b]  (coalesced reads in kernel B)
__global__ __launch_bounds__(BLK_A) void sums_kernel(const float* __restrict__ x,
                                                     const float* __restrict__ y,
                                                     float* __restrict__ ws,
                                                     double* __restrict__ acc_out,
                                                     unsigned* __restrict__ cnt)
{
    // Re-zero the fused-final accumulator/counter each launch (graph-replay safe;
    // kernel B is stream-ordered after this kernel completes).
    if (blockIdx.x == 0 && threadIdx.x == 0) { *acc_out = 0.0; *cnt = 0u; }

    const int wave = threadIdx.x >> 6;
    const int lane = threadIdx.x & 63;
    const int b = blockIdx.x * WAVES_PER_BLOCK + wave;

    const f3* __restrict__ xb = reinterpret_cast<const f3*>(x) + (size_t)b * N_PTS;
    const f3* __restrict__ yb = reinterpret_cast<const f3*>(y) + (size_t)b * N_PTS;

    float a[17];
    #pragma unroll
    for (int k = 0; k < 17; k++) a[k] = 0.f;

    #pragma unroll
    for (int p = 0; p < 8; p++) {
        f3 X = xb[p * 64 + lane];
        f3 Y = yb[p * 64 + lane];
        a[0] += X.x;  a[1] += X.y;  a[2] += X.z;
        a[3] += Y.x;  a[4] += Y.y;  a[5] += Y.z;
        a[6]  += X.x*Y.x; a[7]  += X.x*Y.y; a[8]  += X.x*Y.z;
        a[9]  += X.y*Y.x; a[10] += X.y*Y.y; a[11] += X.y*Y.z;
        a[12] += X.z*Y.x; a[13] += X.z*Y.y; a[14] += X.z*Y.z;
        a[15] += X.x*X.x + X.y*X.y + X.z*X.z;
        a[16] += Y.x*Y.x + Y.y*Y.y + Y.z*Y.z;
    }

    #pragma unroll
    for (int k = 0; k < 17; k++) a[k] = dpp_wave_sum(a[k]);

    if (lane == 63) {
        #pragma unroll
        for (int k = 0; k < 17; k++) ws[k * B_TOT + b] = a[k];
    }
}

// ---------------- Kernel B: per-batch Kabsch (f64) + fused final mean --------
__global__ __launch_bounds__(256) void solve_kernel(const float* __restrict__ ws,
                                                    double* __restrict__ acc_out,
                                                    unsigned* __restrict__ cnt,
                                                    float* __restrict__ out)
{
    const int b = blockIdx.x * 256 + threadIdx.x;

    double S[17];
    #pragma unroll
    for (int k = 0; k < 17; k++) S[k] = (double)ws[k * B_TOT + b];

    const double Nn = (double)N_PTS;
    double mx[3] = {S[0]/Nn, S[1]/Nn, S[2]/Nn};
    double my[3] = {S[3]/Nn, S[4]/Nn, S[5]/Nn};

    double C[3][3];
    #pragma unroll
    for (int d = 0; d < 3; d++)
        #pragma unroll
        for (int e = 0; e < 3; e++)
            C[d][e] = S[6 + d*3 + e] - Nn * mx[d] * my[e];

    double sxx = S[15] - Nn*(mx[0]*mx[0] + mx[1]*mx[1] + mx[2]*mx[2]);
    double syy = S[16] - Nn*(my[0]*my[0] + my[1]*my[1] + my[2]*my[2]);

    // K = C^T C (symmetric)
    double K00=0,K01=0,K02=0,K11=0,K12=0,K22=0;
    #pragma unroll
    for (int k = 0; k < 3; k++) {
        K00 += C[k][0]*C[k][0]; K01 += C[k][0]*C[k][1]; K02 += C[k][0]*C[k][2];
        K11 += C[k][1]*C[k][1]; K12 += C[k][1]*C[k][2]; K22 += C[k][2]*C[k][2];
    }

    // closed-form symmetric 3x3 eigenvalues
    double q3 = (K00 + K11 + K22) / 3.0;
    double p1 = K01*K01 + K02*K02 + K12*K12;
    double a00 = K00 - q3, a11 = K11 - q3, a22 = K22 - q3;
    double p2 = a00*a00 + a11*a11 + a22*a22 + 2.0*p1;
    double lam1, lam2, lam3;
    if (p2 <= 1e-300) {
        lam1 = lam2 = lam3 = q3;
    } else {
        double pp  = sqrt(p2 / 6.0);
        double ip  = 1.0 / pp;
        double b00 = a00*ip, b11 = a11*ip, b22 = a22*ip;
        double b01 = K01*ip, b02 = K02*ip, b12 = K12*ip;
        double detB = b00*(b11*b22 - b12*b12)
                    - b01*(b01*b22 - b12*b02)
                    + b02*(b01*b12 - b11*b02);
        double r = 0.5 * detB;
        r = fmin(1.0, fmax(-1.0, r));
        double phi = acos(r) / 3.0;
        lam1 = q3 + 2.0*pp*cos(phi);
        lam3 = q3 + 2.0*pp*cos(phi + 2.0943951023931954923);  // +2*pi/3
        lam2 = 3.0*q3 - lam1 - lam3;
    }
    lam1 = fmax(lam1, 0.0); lam2 = fmax(lam2, 0.0); lam3 = fmax(lam3, 0.0);
    double s1 = sqrt(lam1), s2 = sqrt(lam2), s3 = sqrt(lam3);

    double detC = C[0][0]*(C[1][1]*C[2][2] - C[1][2]*C[2][1])
                - C[0][1]*(C[1][0]*C[2][2] - C[1][2]*C[2][0])
                + C[0][2]*(C[1][0]*C[2][1] - C[1][1]*C[2][0]);
    double sgn = (detC < 0.0) ? -1.0 : 1.0;
    double trRC = s1 + s2 + sgn * s3;

    double v = sxx + syy - 2.0 * trRC;

    // block reduction (f64)
    #pragma unroll
    for (int off = 32; off; off >>= 1) v += __shfl_down(v, off, 64);
    __shared__ double red[4];
    const int wave = threadIdx.x >> 6, lane = threadIdx.x & 63;
    if (lane == 0) red[wave] = v;
    __syncthreads();

    // fused final: 32 uncontended f64 atomics, last block writes the mean
    if (threadIdx.x == 0) {
        double blk = red[0] + red[1] + red[2] + red[3];
        atomicAdd(acc_out, blk);
        __threadfence();
        unsigned t = atomicAdd(cnt, 1u);
        if (t == gridDim.x - 1) {
            __threadfence();
            double total = atomicAdd(acc_out, 0.0);  // atomic read at L2
            out[0] = (float)(total / ((double)B_TOT * (double)N_PTS * 3.0));
        }
    }
}

extern "C" void kernel_launch(void* const* d_in, const int* in_sizes, int n_in,
                              void* d_out, int out_size, void* d_ws, size_t ws_size,
                              hipStream_t stream) {
    const float* x = (const float*)d_in[0];   // input  (B,N,3) fp32
    const float* y = (const float*)d_in[1];   // target (B,N,3) fp32
    float* out = (float*)d_out;

    float*    ws  = (float*)d_ws;                                   // 17*8192 floats
    double*   acc = (double*)((char*)d_ws + 17 * B_TOT * 4);        // 8B-aligned
    unsigned* cnt = (unsigned*)((char*)d_ws + 17 * B_TOT * 4 + 8);

    sums_kernel <<<B_TOT / WAVES_PER_BLOCK, BLK_A, 0, stream>>>(x, y, ws, acc, cnt);
    solve_kernel<<<B_TOT / 256, 256, 0, stream>>>(ws, acc, cnt, out);
}